// Round 1
// baseline (795.505 us; speedup 1.0000x reference)
//
#include <hip/hip_runtime.h>

#define BS 2
#define NN 65536
#define CC 256
#define KNNK 16

typedef short bf16x8 __attribute__((ext_vector_type(8)));
typedef float f32x4 __attribute__((ext_vector_type(4)));

__device__ __forceinline__ unsigned f2bf(float f) {
  unsigned u = __builtin_bit_cast(unsigned, f);
  return (u + 0x7FFFu + ((u >> 16) & 1u)) >> 16;  // RNE
}
__device__ __forceinline__ int pack2(float a, float b) {
  return (int)(f2bf(a) | (f2bf(b) << 16));
}
__device__ __forceinline__ float bfu(unsigned short v) {
  return __builtin_bit_cast(float, ((unsigned)v) << 16);
}
__device__ __forceinline__ float bflo(unsigned u) { return __builtin_bit_cast(float, u << 16); }
__device__ __forceinline__ float bfhi(unsigned u) { return __builtin_bit_cast(float, u & 0xFFFF0000u); }

// out[m][n] = sum_k A[m][k] * W[n][k] + bias[n]; A:(131072,256) fp32, W:(256,256) fp32.
// bf16 conversion fused into LDS staging. TM=128, TN=256(full), BK=32.
// LDS row stride 40 bf16 (80B=20 banks): frag b128 reads <=2-way conflicts (free).
template <int OUT_BF16>
__global__ __launch_bounds__(512)
void proj_kernel(const float* __restrict__ A, const float* __restrict__ W,
                 const float* __restrict__ bias, void* __restrict__ Out) {
  constexpr int K = 256, TM = 128, LDS_S = 40;
  __shared__ __align__(16) unsigned short As[TM * LDS_S];    // 10240 B
  __shared__ __align__(16) unsigned short Bs[256 * LDS_S];   // 20480 B
  const int t = threadIdx.x;
  const int wave = t >> 6;
  const int lane = t & 63;
  const int wm = wave >> 2, wn = wave & 3;         // 2x4 waves of 64x64
  const int lrow = lane & 15, quad = lane >> 4;
  const long row0 = (long)blockIdx.x * TM;

  const int ar = t >> 2, akb = t & 3;  // A staging: row ar, 8 k-elems at akb*8
  const int br = t >> 1, bkb = t & 1;  // B staging: row br, 16 k-elems at bkb*16
  const float* aptr = A + (row0 + ar) * K + akb * 8;
  const float* bptr = W + (long)br * K + bkb * 16;

  f32x4 acc[4][4];
#pragma unroll
  for (int i = 0; i < 4; ++i)
#pragma unroll
    for (int j = 0; j < 4; ++j) acc[i][j] = f32x4{0.f, 0.f, 0.f, 0.f};

  for (int k0 = 0; k0 < K; k0 += 32) {
    float4 a0 = *(const float4*)(aptr + k0);
    float4 a1 = *(const float4*)(aptr + k0 + 4);
    float4 b0 = *(const float4*)(bptr + k0);
    float4 b1 = *(const float4*)(bptr + k0 + 4);
    float4 b2 = *(const float4*)(bptr + k0 + 8);
    float4 b3 = *(const float4*)(bptr + k0 + 12);
    __syncthreads();  // previous iter's compute done before overwrite
    *(int4*)&As[ar * LDS_S + akb * 8] =
        make_int4(pack2(a0.x, a0.y), pack2(a0.z, a0.w), pack2(a1.x, a1.y), pack2(a1.z, a1.w));
    *(int4*)&Bs[br * LDS_S + bkb * 16] =
        make_int4(pack2(b0.x, b0.y), pack2(b0.z, b0.w), pack2(b1.x, b1.y), pack2(b1.z, b1.w));
    *(int4*)&Bs[br * LDS_S + bkb * 16 + 8] =
        make_int4(pack2(b2.x, b2.y), pack2(b2.z, b2.w), pack2(b3.x, b3.y), pack2(b3.z, b3.w));
    __syncthreads();
    bf16x8 af[4], bfr[4];
#pragma unroll
    for (int mi = 0; mi < 4; ++mi)
      af[mi] = *(const bf16x8*)&As[(wm * 64 + mi * 16 + lrow) * LDS_S + quad * 8];
#pragma unroll
    for (int ni = 0; ni < 4; ++ni)
      bfr[ni] = *(const bf16x8*)&Bs[(wn * 64 + ni * 16 + lrow) * LDS_S + quad * 8];
#pragma unroll
    for (int mi = 0; mi < 4; ++mi)
#pragma unroll
      for (int ni = 0; ni < 4; ++ni)
        acc[mi][ni] = __builtin_amdgcn_mfma_f32_16x16x32_bf16(af[mi], bfr[ni], acc[mi][ni], 0, 0, 0);
  }

  // C/D layout: col = lane&15, row = quad*4 + reg  (m89-verified)
#pragma unroll
  for (int mi = 0; mi < 4; ++mi)
#pragma unroll
    for (int ni = 0; ni < 4; ++ni) {
      const long gr0 = row0 + wm * 64 + mi * 16 + quad * 4;
      const int gc = wn * 64 + ni * 16 + lrow;
      const float bv = bias[gc];
#pragma unroll
      for (int r = 0; r < 4; ++r) {
        float v = acc[mi][ni][r] + bv;
        if (OUT_BF16)
          ((unsigned short*)Out)[(gr0 + r) * 256 + gc] = (unsigned short)f2bf(v);
        else
          ((float*)Out)[(gr0 + r) * 256 + gc] = v;
      }
    }
}

// One 256-thread block per (b, n). Dot phase: thread=(k=t>>4, cg=t&15) covers 16 channels.
// V phase: thread = channel. LN fused.
__global__ __launch_bounds__(256)
void attn_kernel(const float* __restrict__ Qp, const unsigned short* __restrict__ Kp,
                 const unsigned short* __restrict__ Vp, const int* __restrict__ knn,
                 const float* __restrict__ ln_g, const float* __restrict__ ln_b,
                 float* __restrict__ out) {
  const int n = blockIdx.x, b = blockIdx.y, t = threadIdx.x;
  __shared__ int sidx[KNNK];
  __shared__ float sdots[KNNK];
  __shared__ float sred[8];
  if (t < KNNK) sidx[t] = knn[n * KNNK + t];
  __syncthreads();

  const long base = ((long)b * NN + n) * CC;
  const long kbase = (long)b * NN * CC;
  int nbr[KNNK];
#pragma unroll
  for (int i = 0; i < KNNK; ++i) nbr[i] = sidx[i];

  // ---- QK^T dot for neighbor k over this thread's 16 channels ----
  const int k = t >> 4, cg = t & 15;
  {
    const float* qp = Qp + base + cg * 16;
    float4 q0 = *(const float4*)(qp);
    float4 q1 = *(const float4*)(qp + 4);
    float4 q2 = *(const float4*)(qp + 8);
    float4 q3 = *(const float4*)(qp + 12);
    const unsigned short* kr = Kp + kbase + (long)nbr[k] * CC + cg * 16;
    int4 kv0 = *(const int4*)(kr);
    int4 kv1 = *(const int4*)(kr + 8);
    float p = q0.x * bflo(kv0.x) + q0.y * bfhi(kv0.x)
            + q0.z * bflo(kv0.y) + q0.w * bfhi(kv0.y)
            + q1.x * bflo(kv0.z) + q1.y * bfhi(kv0.z)
            + q1.z * bflo(kv0.w) + q1.w * bfhi(kv0.w)
            + q2.x * bflo(kv1.x) + q2.y * bfhi(kv1.x)
            + q2.z * bflo(kv1.y) + q2.w * bfhi(kv1.y)
            + q3.x * bflo(kv1.z) + q3.y * bfhi(kv1.z)
            + q3.z * bflo(kv1.w) + q3.w * bfhi(kv1.w);
#pragma unroll
    for (int m = 1; m < 16; m <<= 1) p += __shfl_xor(p, m);
    if (cg == 0) sdots[k] = p * 0.0625f;  // 1/sqrt(256)
  }
  __syncthreads();

  // ---- softmax (replicated per thread; cheap) ----
  float d[KNNK];
#pragma unroll
  for (int i = 0; i < KNNK; ++i) d[i] = sdots[i];
  float mx = d[0];
#pragma unroll
  for (int i = 1; i < KNNK; ++i) mx = fmaxf(mx, d[i]);
  float s = 0.f;
#pragma unroll
  for (int i = 0; i < KNNK; ++i) { d[i] = __expf(d[i] - mx); s += d[i]; }
  const float inv = 1.0f / s;

  // ---- weighted V sum: thread = channel t ----
  float o = 0.f;
#pragma unroll
  for (int i = 0; i < KNNK; ++i)
    o += d[i] * bfu(Vp[kbase + (long)nbr[i] * CC + t]);
  o *= inv;
  o += Qp[base + t];  // residual (fp32)

  // ---- LayerNorm over 256 channels ----
  float s1 = o, s2 = o * o;
#pragma unroll
  for (int m = 1; m < 64; m <<= 1) {
    s1 += __shfl_xor(s1, m);
    s2 += __shfl_xor(s2, m);
  }
  const int wv = t >> 6;
  if ((t & 63) == 0) { sred[wv] = s1; sred[wv + 4] = s2; }
  __syncthreads();
  const float S1 = sred[0] + sred[1] + sred[2] + sred[3];
  const float S2 = sred[4] + sred[5] + sred[6] + sred[7];
  const float mu = S1 * (1.0f / 256.0f);
  const float var = S2 * (1.0f / 256.0f) - mu * mu;
  const float rs = rsqrtf(var + 1e-5f);
  out[base + t] = (o - mu) * rs * ln_g[t] + ln_b[t];
}

extern "C" void kernel_launch(void* const* d_in, const int* in_sizes, int n_in,
                              void* d_out, int out_size, void* d_ws, size_t ws_size,
                              hipStream_t stream) {
  const float* Q   = (const float*)d_in[0];
  const float* K   = (const float*)d_in[1];
  const float* V   = (const float*)d_in[2];
  const int*   knn = (const int*)d_in[3];
  const float* Wq  = (const float*)d_in[4];
  const float* Wqb = (const float*)d_in[5];
  const float* Wk  = (const float*)d_in[6];
  const float* Wkb = (const float*)d_in[7];
  const float* Wv  = (const float*)d_in[8];
  const float* Wvb = (const float*)d_in[9];
  const float* ln_g = (const float*)d_in[10];
  const float* ln_b = (const float*)d_in[11];
  float* out = (float*)d_out;

  // workspace layout: Qp fp32 (134.2 MB) | Kp bf16 (67.1 MB) | Vp bf16 (67.1 MB)
  float* Qp = (float*)d_ws;
  unsigned short* Kp = (unsigned short*)((char*)d_ws + (size_t)BS * NN * CC * 4);
  unsigned short* Vp = Kp + (size_t)BS * NN * CC;

  proj_kernel<0><<<1024, 512, 0, stream>>>(Q, Wq, Wqb, (void*)Qp);
  proj_kernel<1><<<1024, 512, 0, stream>>>(K, Wk, Wkb, (void*)Kp);
  proj_kernel<1><<<1024, 512, 0, stream>>>(V, Wv, Wvb, (void*)Vp);
  attn_kernel<<<dim3(NN, BS), 256, 0, stream>>>(Qp, Kp, Vp, knn, ln_g, ln_b, out);
}